// Round 13
// baseline (159.313 us; speedup 1.0000x reference)
//
#include <hip/hip_runtime.h>
#include <hip/hip_bf16.h>

#define BSZ   4
#define NTOK  1024
#define DIN   384
#define DST   16
#define MROWS (BSZ * NTOK)     // 4096
#define KDIM  384
#define NM    (MROWS * DIN)    // 1572864 elements per plane

typedef __attribute__((ext_vector_type(8))) short bf16x8;
typedef __attribute__((ext_vector_type(4))) float f32x4;

__device__ __forceinline__ float softplus_f(float z) {
  return (z > 20.0f) ? z : log1pf(expf(z));
}

__device__ __forceinline__ unsigned short f32_to_bf16(float f) {
  unsigned int u = __float_as_uint(f);
  unsigned int rnd = 0x7fffu + ((u >> 16) & 1u);   // round-to-nearest-even
  return (unsigned short)((u + rnd) >> 16);
}

__device__ __forceinline__ float bf16_lo(unsigned int w) { return __uint_as_float(w << 16); }
__device__ __forceinline__ float bf16_hi(unsigned int w) { return __uint_as_float(w & 0xffff0000u); }

// ---------------------------------------------------------------------------
// Kernel W: concat(Wdts|Wdtd|WB|WC|0) f32 -> bf16 rows Wb[832][384]
// ---------------------------------------------------------------------------
__global__ __launch_bounds__(256) void wconv_kernel(
    const float* __restrict__ Wdts, const float* __restrict__ Wdtd,
    const float* __restrict__ WB,   const float* __restrict__ WC,
    unsigned short* __restrict__ Wb)
{
  const int idx8 = (blockIdx.x * 256 + threadIdx.x) * 8;   // 156 blocks
  const int row = idx8 / KDIM;
  const int k   = idx8 % KDIM;
  uint4 o = make_uint4(0u, 0u, 0u, 0u);
  if (row < 800) {
    const float* src;
    if (row < 384)      src = Wdts + (long)row * KDIM + k;
    else if (row < 768) src = Wdtd + (long)(row - 384) * KDIM + k;
    else if (row < 784) src = WB   + (long)(row - 768) * KDIM + k;
    else                src = WC   + (long)(row - 784) * KDIM + k;
    float4 v0 = *(const float4*)src;
    float4 v1 = *(const float4*)(src + 4);
    o.x = (unsigned int)f32_to_bf16(v0.x) | ((unsigned int)f32_to_bf16(v0.y) << 16);
    o.y = (unsigned int)f32_to_bf16(v0.z) | ((unsigned int)f32_to_bf16(v0.w) << 16);
    o.z = (unsigned int)f32_to_bf16(v1.x) | ((unsigned int)f32_to_bf16(v1.y) << 16);
    o.w = (unsigned int)f32_to_bf16(v1.z) | ((unsigned int)f32_to_bf16(v1.w) << 16);
  }
  *(uint4*)&Wb[idx8] = o;
}

// ---------------------------------------------------------------------------
// Kernel 0: x (b,n,d) -> xT (b,d,n) f32  AND  xb (b,n,d) bf16 (for MFMA).
// ---------------------------------------------------------------------------
__global__ __launch_bounds__(256) void xpose_kernel(
    const float* __restrict__ x, float* __restrict__ xT,
    unsigned short* __restrict__ xb)
{
  __shared__ float tile[32][33];
  const int n0 = blockIdx.x * 32;
  const int d0 = blockIdx.y * 32;
  const int b  = blockIdx.z;
  const int tx = threadIdx.x & 31, ty = threadIdx.x >> 5;   // ty 0..7
#pragma unroll
  for (int i = 0; i < 4; ++i) {
    int nn = n0 + ty + i * 8;
    float v = x[(long)(b * NTOK + nn) * DIN + d0 + tx];
    tile[ty + i * 8][tx] = v;
    xb[(long)(b * NTOK + nn) * DIN + d0 + tx] = f32_to_bf16(v);
  }
  __syncthreads();
#pragma unroll
  for (int i = 0; i < 4; ++i) {
    int dd = d0 + ty + i * 8;
    xT[(long)(b * DIN + dd) * NTOK + n0 + tx] = tile[tx][ty + i * 8];
  }
}

// ---------------------------------------------------------------------------
// Kernel 1: full projection GEMM via bf16 MFMA (4096 x 832 x 384), BK=64,
// double-buffered LDS, one barrier per k-iter, loads issued AFTER the barrier.
// ---------------------------------------------------------------------------
__global__ __launch_bounds__(256) void proj_mfma_kernel(
    const unsigned short* __restrict__ xb,   // bf16 x, row-major [4096][384]
    const unsigned short* __restrict__ Wb,   // bf16 W, row-major [832][384]
    const float* __restrict__ bdts, const float* __restrict__ bdtd,
    unsigned short* __restrict__ dsT, unsigned short* __restrict__ ddT,
    float* __restrict__ Bmat, float* __restrict__ Cmat)
{
  __shared__ short smem_s[2][2][64 * 72];   // [buf][A|W][64 rows x 72 pad] = 36864 B

  const int t    = threadIdx.x;
  const int bm   = blockIdx.x & 63;         // 64 row tiles
  const int bn   = blockIdx.x >> 6;         // 13 col tiles
  const int row0 = bm * 64;
  const int col0 = bn * 64;                 // 0..831
  const int bat  = row0 >> 10;
  const int n0   = row0 & 1023;

  const int l  = t & 63;
  const int w  = t >> 6;
  const int wr = (w >> 1) * 32;             // wave row base
  const int wc = (w & 1) * 32;              // wave col base
  const int lr = l & 15;
  const int lk = (l >> 4) * 8;              // k offset in frag (bf16)

  const int sr = t >> 2;                    // staging row 0..63
  const int sk = (t & 3) * 16;              // staging k (shorts), 2x uint4

  f32x4 acc[2][2];
  const f32x4 zero = {0.f, 0.f, 0.f, 0.f};
  acc[0][0] = zero; acc[0][1] = zero; acc[1][0] = zero; acc[1][1] = zero;

  uint4 la0, la1, lw0, lw1;
#define PLOAD(K0)                                                          \
  {                                                                        \
    const unsigned short* ap = &xb[(long)(row0 + sr) * KDIM + (K0) + sk];  \
    const unsigned short* wp = &Wb[(long)(col0 + sr) * KDIM + (K0) + sk];  \
    la0 = *(const uint4*)ap;  la1 = *(const uint4*)(ap + 8);               \
    lw0 = *(const uint4*)wp;  lw1 = *(const uint4*)(wp + 8);               \
  }
#define PSTORE(BUF)                                                        \
  {                                                                        \
    *(uint4*)&smem_s[BUF][0][sr * 72 + sk]     = la0;                      \
    *(uint4*)&smem_s[BUF][0][sr * 72 + sk + 8] = la1;                      \
    *(uint4*)&smem_s[BUF][1][sr * 72 + sk]     = lw0;                      \
    *(uint4*)&smem_s[BUF][1][sr * 72 + sk + 8] = lw1;                      \
  }

  PLOAD(0);
  PSTORE(0);

  for (int it = 0; it < 6; ++it) {
    const int cur = it & 1;
    __syncthreads();                        // lds[cur] visible; lds[cur^1] readers done
    if (it + 1 < 6) PLOAD((it + 1) * 64);   // in flight across MFMA + ds_write
    const short* Asm = smem_s[cur][0];
    const short* Wsm = smem_s[cur][1];
#pragma unroll
    for (int kh = 0; kh < 2; ++kh) {
      const int ko = kh * 32 + lk;
      bf16x8 a0 = *(const bf16x8*)&Asm[(wr + lr) * 72 + ko];
      bf16x8 a1 = *(const bf16x8*)&Asm[(wr + 16 + lr) * 72 + ko];
      bf16x8 b0 = *(const bf16x8*)&Wsm[(wc + lr) * 72 + ko];
      bf16x8 b1 = *(const bf16x8*)&Wsm[(wc + 16 + lr) * 72 + ko];
      acc[0][0] = __builtin_amdgcn_mfma_f32_16x16x32_bf16(a0, b0, acc[0][0], 0, 0, 0);
      acc[0][1] = __builtin_amdgcn_mfma_f32_16x16x32_bf16(a0, b1, acc[0][1], 0, 0, 0);
      acc[1][0] = __builtin_amdgcn_mfma_f32_16x16x32_bf16(a1, b0, acc[1][0], 0, 0, 0);
      acc[1][1] = __builtin_amdgcn_mfma_f32_16x16x32_bf16(a1, b1, acc[1][1], 0, 0, 0);
    }
    if (it + 1 < 6) PSTORE(cur ^ 1);        // vmcnt wait lands here, after MFMA
  }

  if (bn < 12) {
    const float* bias = (bn < 6) ? bdts : bdtd;
    unsigned short* plane = (bn < 6) ? dsT : ddT;
    const int dbase = (bn < 6) ? col0 : col0 - 384;
    const float bv0 = bias[dbase + wc + lr];
    const float bv1 = bias[dbase + wc + 16 + lr];
    __syncthreads();
    unsigned short* outl = (unsigned short*)smem_s;   // [64 d][72 n] u16
#pragma unroll
    for (int i = 0; i < 2; ++i)
#pragma unroll
      for (int j = 0; j < 2; ++j) {
        const float bb = j ? bv1 : bv0;
        const int cl = wc + j * 16 + lr;
#pragma unroll
        for (int q = 0; q < 4; ++q) {
          const int nl = wr + i * 16 + (l >> 4) * 4 + q;
          float dl = fminf(softplus_f(acc[i][j][q] + bb), 0.15f);
          outl[cl * 72 + nl] = f32_to_bf16(dl);
        }
      }
    __syncthreads();
    const int dl = t >> 2;
    const int seg = t & 3;
    uint4 w0 = *(const uint4*)&outl[dl * 72 + seg * 16];
    uint4 w1 = *(const uint4*)&outl[dl * 72 + seg * 16 + 8];
    long addr = (long)(bat * DIN + dbase + dl) * NTOK + n0 + seg * 16;
    *(uint4*)&plane[addr]     = w0;
    *(uint4*)&plane[addr + 8] = w1;
  } else {
#pragma unroll
    for (int i = 0; i < 2; ++i)
#pragma unroll
      for (int j = 0; j < 2; ++j) {
        const int cl = wc + j * 16 + lr;
#pragma unroll
        for (int q = 0; q < 4; ++q) {
          const int row = row0 + wr + i * 16 + (l >> 4) * 4 + q;
          if (cl < 16)       Bmat[(long)row * DST + cl] = acc[i][j][q];
          else if (cl < 32)  Cmat[(long)row * DST + (cl - 16)] = acc[i][j][q];
        }
      }
  }
#undef PLOAD
#undef PSTORE
}

// ---------------------------------------------------------------------------
// Kernel 2: per-(b,d) recurrence, s-SPLIT across threads. 1024 threads:
//   sidx = t>>9 owns states [sidx*8, sidx*8+8); rows tr=t&511 and tr+512.
// Per-thread state halves (hreg+h0r = 32 f32) -> launch_bounds(1024,8)
// targets VGPR<=64 -> 32 waves/CU (round-12: VGPR 76 capped us at 16).
// h half-planes in LDS: one uint4/row, quad-swizzled so every 8-lane b128
// group covers all 32 banks: qoff(n) = (n>>3)*8 + ((n&3)<<1) + ((n>>2)&1).
// (n&7) invariant under n+-32 -> u/d reads also conflict-free.
// ---------------------------------------------------------------------------
#define QOFF(n) ((((n) >> 3) << 3) + (((n) & 3) << 1) + (((n) >> 2) & 1))

__global__ __launch_bounds__(1024, 8) void ssm_kernel(
    const float* __restrict__ xT,
    const unsigned short* __restrict__ dsT,
    const unsigned short* __restrict__ ddT,
    const float* __restrict__ Bmat, const float* __restrict__ Cmat,
    const float* __restrict__ Dparam, const float* __restrict__ Alog,
    const float* __restrict__ diffraw, const int* __restrict__ Kp,
    float* __restrict__ yT)
{
  __shared__ unsigned int hp[2][NTOK * 4];  // two 16 KB half-planes (bf16 h)
  __shared__ float A_sh[16];
  const int t    = threadIdx.x;
  const int sidx = t >> 9;                  // s-half 0/1
  const int tr   = t & 511;
  const int d = blockIdx.x % DIN;
  const int b = blockIdx.x / DIN;
  const int K = Kp[0];
  const float dt = 1.0f / (float)K;
  const float Dc = 0.5f / (1.0f + expf(-diffraw[d]));
  const float Dp = Dparam[d];

  if (t < 16)
    A_sh[t] = -log1pf(expf(Alog[d * DST + t]));

  const long col = (long)(b * DIN + d) * NTOK;
  unsigned int* hme = hp[sidx];

  float hreg[2][8], h0r[2][8], a1[2], a2[2], resid[2];
#pragma unroll
  for (int j = 0; j < 2; ++j) {
    const int n = tr + j * 512;
    float xv = xT[col + n];
    resid[j] = xv * Dp;
    float dsv = __uint_as_float((unsigned int)dsT[col + n] << 16);
    float ddv = __uint_as_float((unsigned int)ddT[col + n] << 16);
    a1[j] = dt * dsv;
    a2[j] = dt * ddv * Dc;
    const float4* Bp = (const float4*)&Bmat[(long)(b * NTOK + n) * DST + sidx * 8];
    float4 b0 = Bp[0], b1 = Bp[1];
    h0r[j][0] = xv * b0.x; h0r[j][1] = xv * b0.y; h0r[j][2] = xv * b0.z; h0r[j][3] = xv * b0.w;
    h0r[j][4] = xv * b1.x; h0r[j][5] = xv * b1.y; h0r[j][6] = xv * b1.z; h0r[j][7] = xv * b1.w;
#pragma unroll
    for (int s = 0; s < 8; ++s) hreg[j][s] = h0r[j][s];
    uint4 pk;
    pk.x = (__float_as_uint(hreg[j][0]) >> 16) | (__float_as_uint(hreg[j][1]) & 0xffff0000u);
    pk.y = (__float_as_uint(hreg[j][2]) >> 16) | (__float_as_uint(hreg[j][3]) & 0xffff0000u);
    pk.z = (__float_as_uint(hreg[j][4]) >> 16) | (__float_as_uint(hreg[j][5]) & 0xffff0000u);
    pk.w = (__float_as_uint(hreg[j][6]) >> 16) | (__float_as_uint(hreg[j][7]) & 0xffff0000u);
    *(uint4*)&hme[QOFF(n) * 4] = pk;
  }
  __syncthreads();

  for (int k = 0; k < K; ++k) {
#pragma unroll
    for (int j = 0; j < 2; ++j) {
      const int n = tr + j * 512;
      const int r = n >> 5, c = n & 31;
      const int nu = (r > 0)  ? n - 32 : n;
      const int nd = (r < 31) ? n + 32 : n;
      const int nl = (c > 0)  ? n - 1  : n;
      const int nr = (c < 31) ? n + 1  : n;
      uint4 qu = *(const uint4*)&hme[QOFF(nu) * 4];
      uint4 qd = *(const uint4*)&hme[QOFF(nd) * 4];
      uint4 ql = *(const uint4*)&hme[QOFF(nl) * 4];
      uint4 qr = *(const uint4*)&hme[QOFF(nr) * 4];
      float lap[8];
#pragma unroll
      for (int ww = 0; ww < 4; ++ww) {
        unsigned int uw = (&qu.x)[ww], dw = (&qd.x)[ww];
        unsigned int lw = (&ql.x)[ww], rw = (&qr.x)[ww];
        lap[2*ww]   = (bf16_lo(uw) + bf16_lo(dw)) + (bf16_lo(lw) + bf16_lo(rw));
        lap[2*ww+1] = (bf16_hi(uw) + bf16_hi(dw)) + (bf16_hi(lw) + bf16_hi(rw));
      }
#pragma unroll
      for (int e = 0; e < 8; ++e) {
        float ce = hreg[j][e];
        float lp = lap[e] - 4.0f * ce;
        float t1 = fmaf(A_sh[sidx * 8 + e], ce, h0r[j][e]);
        float hv = fmaf(a1[j], t1, ce);
        hreg[j][e] = fmaf(a2[j], lp, hv);
      }
    }
    if (k + 1 < K) {
      __syncthreads();
#pragma unroll
      for (int j = 0; j < 2; ++j) {
        const int n = tr + j * 512;
        uint4 pk;
        pk.x = (__float_as_uint(hreg[j][0]) >> 16) | (__float_as_uint(hreg[j][1]) & 0xffff0000u);
        pk.y = (__float_as_uint(hreg[j][2]) >> 16) | (__float_as_uint(hreg[j][3]) & 0xffff0000u);
        pk.z = (__float_as_uint(hreg[j][4]) >> 16) | (__float_as_uint(hreg[j][5]) & 0xffff0000u);
        pk.w = (__float_as_uint(hreg[j][6]) >> 16) | (__float_as_uint(hreg[j][7]) & 0xffff0000u);
        *(uint4*)&hme[QOFF(n) * 4] = pk;
      }
      __syncthreads();
    }
  }

  // C contraction over this thread's 8 states; combine halves via LDS.
  float part[2];
#pragma unroll
  for (int j = 0; j < 2; ++j) {
    const int n = tr + j * 512;
    const float4* Cp = (const float4*)&Cmat[(long)(b * NTOK + n) * DST + sidx * 8];
    float4 c0 = Cp[0], c1 = Cp[1];
    part[j] = hreg[j][0] * c0.x + hreg[j][1] * c0.y + hreg[j][2] * c0.z + hreg[j][3] * c0.w +
              hreg[j][4] * c1.x + hreg[j][5] * c1.y + hreg[j][6] * c1.z + hreg[j][7] * c1.w;
  }
  __syncthreads();                          // all k-loop LDS reads done
  float* P = (float*)hp;                    // reuse: [sidx][j][tr] f32
  P[sidx * 1024 + 0 * 512 + tr] = part[0];
  P[sidx * 1024 + 1 * 512 + tr] = part[1];
  __syncthreads();
  if (sidx == 0) {
#pragma unroll
    for (int j = 0; j < 2; ++j) {
      const int n = tr + j * 512;
      yT[col + n] = part[j] + P[1024 + j * 512 + tr] + resid[j];
    }
  }
}

// ---------------------------------------------------------------------------
// Kernel 3: yT (b,d,n) -> out (b,n,d), both sides coalesced via LDS tile.
// ---------------------------------------------------------------------------
__global__ __launch_bounds__(256) void untranspose_kernel(
    const float* __restrict__ yT, float* __restrict__ out)
{
  __shared__ float tile[32][33];
  const int n0 = blockIdx.x * 32;
  const int d0 = blockIdx.y * 32;
  const int b  = blockIdx.z;
  const int tx = threadIdx.x & 31, ty = threadIdx.x >> 5;
#pragma unroll
  for (int i = 0; i < 4; ++i) {
    int dd = d0 + ty + i * 8;
    tile[ty + i * 8][tx] = yT[(long)(b * DIN + dd) * NTOK + n0 + tx];
  }
  __syncthreads();
#pragma unroll
  for (int i = 0; i < 4; ++i) {
    int nn = n0 + ty + i * 8;
    out[(long)(b * NTOK + nn) * DIN + d0 + tx] = tile[tx][ty + i * 8];
  }
}

extern "C" void kernel_launch(void* const* d_in, const int* in_sizes, int n_in,
                              void* d_out, int out_size, void* d_ws, size_t ws_size,
                              hipStream_t stream) {
  const float* x     = (const float*)d_in[0];
  const float* Wdts  = (const float*)d_in[1];
  const float* bdts  = (const float*)d_in[2];
  const float* Wdtd  = (const float*)d_in[3];
  const float* bdtd  = (const float*)d_in[4];
  const float* WB    = (const float*)d_in[5];
  const float* WC    = (const float*)d_in[6];
  const float* Dpar  = (const float*)d_in[7];
  const float* Alog  = (const float*)d_in[8];
  const float* diffr = (const float*)d_in[9];
  const int*   Kst   = (const int*)d_in[10];

  // ws layout (13.1 MB): Bmat | Cmat | xT | yT.  xb+Wb alias the yT region
  // (dead until ssm writes yT — stream-ordered).
  float* Bmat = (float*)d_ws;
  float* Cmat = Bmat + (long)MROWS * DST;
  float* xT   = Cmat + (long)MROWS * DST;
  float* yT   = xT + NM;
  unsigned short* xb = (unsigned short*)yT;        // NM bf16 (3.1 MB)
  unsigned short* Wb = xb + NM;                    // 832*384 bf16 (0.64 MB)

  // d_out scratch: bf16 delta planes between proj and ssm
  unsigned short* dsT = (unsigned short*)d_out;
  unsigned short* ddT = dsT + NM;

  wconv_kernel<<<dim3(156), dim3(256), 0, stream>>>(Wdts, Wdtd, WB, WC, Wb);

  xpose_kernel<<<dim3(NTOK / 32, DIN / 32, BSZ), dim3(256), 0, stream>>>(x, xT, xb);

  proj_mfma_kernel<<<dim3(64 * 13), dim3(256), 0, stream>>>(
      xb, Wb, bdts, bdtd, dsT, ddT, Bmat, Cmat);

  ssm_kernel<<<dim3(BSZ * DIN), dim3(1024), 0, stream>>>(
      xT, dsT, ddT, Bmat, Cmat, Dpar, Alog, diffr, Kst, yT);

  untranspose_kernel<<<dim3(NTOK / 32, DIN / 32, BSZ), dim3(256), 0, stream>>>(
      yT, (float*)d_out);
}

// Round 14
// 74.689 us; speedup vs baseline: 2.1330x; 2.1330x over previous
//
#include <hip/hip_runtime.h>
#include <hip/hip_bf16.h>

#define BSZ   4
#define NTOK  1024
#define DIN   384
#define DST   16
#define MROWS (BSZ * NTOK)     // 4096
#define KDIM  384
#define NM    (MROWS * DIN)    // 1572864 elements per plane

typedef __attribute__((ext_vector_type(8))) short bf16x8;
typedef __attribute__((ext_vector_type(4))) float f32x4;

__device__ __forceinline__ float softplus_f(float z) {
  return (z > 20.0f) ? z : log1pf(expf(z));
}

__device__ __forceinline__ unsigned short f32_to_bf16(float f) {
  unsigned int u = __float_as_uint(f);
  unsigned int rnd = 0x7fffu + ((u >> 16) & 1u);   // round-to-nearest-even
  return (unsigned short)((u + rnd) >> 16);
}

__device__ __forceinline__ float bf16_lo(unsigned int w) { return __uint_as_float(w << 16); }
__device__ __forceinline__ float bf16_hi(unsigned int w) { return __uint_as_float(w & 0xffff0000u); }

// ---------------------------------------------------------------------------
// Kernel W: concat(Wdts|Wdtd|WB|WC|0) f32 -> bf16 rows Wb[832][384]
// ---------------------------------------------------------------------------
__global__ __launch_bounds__(256) void wconv_kernel(
    const float* __restrict__ Wdts, const float* __restrict__ Wdtd,
    const float* __restrict__ WB,   const float* __restrict__ WC,
    unsigned short* __restrict__ Wb)
{
  const int idx8 = (blockIdx.x * 256 + threadIdx.x) * 8;   // 156 blocks
  const int row = idx8 / KDIM;
  const int k   = idx8 % KDIM;
  uint4 o = make_uint4(0u, 0u, 0u, 0u);
  if (row < 800) {
    const float* src;
    if (row < 384)      src = Wdts + (long)row * KDIM + k;
    else if (row < 768) src = Wdtd + (long)(row - 384) * KDIM + k;
    else if (row < 784) src = WB   + (long)(row - 768) * KDIM + k;
    else                src = WC   + (long)(row - 784) * KDIM + k;
    float4 v0 = *(const float4*)src;
    float4 v1 = *(const float4*)(src + 4);
    o.x = (unsigned int)f32_to_bf16(v0.x) | ((unsigned int)f32_to_bf16(v0.y) << 16);
    o.y = (unsigned int)f32_to_bf16(v0.z) | ((unsigned int)f32_to_bf16(v0.w) << 16);
    o.z = (unsigned int)f32_to_bf16(v1.x) | ((unsigned int)f32_to_bf16(v1.y) << 16);
    o.w = (unsigned int)f32_to_bf16(v1.z) | ((unsigned int)f32_to_bf16(v1.w) << 16);
  }
  *(uint4*)&Wb[idx8] = o;
}

// ---------------------------------------------------------------------------
// Kernel 0: x (b,n,d) -> xT (b,d,n) f32  AND  xb (b,n,d) bf16 (for MFMA).
// ---------------------------------------------------------------------------
__global__ __launch_bounds__(256) void xpose_kernel(
    const float* __restrict__ x, float* __restrict__ xT,
    unsigned short* __restrict__ xb)
{
  __shared__ float tile[32][33];
  const int n0 = blockIdx.x * 32;
  const int d0 = blockIdx.y * 32;
  const int b  = blockIdx.z;
  const int tx = threadIdx.x & 31, ty = threadIdx.x >> 5;   // ty 0..7
#pragma unroll
  for (int i = 0; i < 4; ++i) {
    int nn = n0 + ty + i * 8;
    float v = x[(long)(b * NTOK + nn) * DIN + d0 + tx];
    tile[ty + i * 8][tx] = v;
    xb[(long)(b * NTOK + nn) * DIN + d0 + tx] = f32_to_bf16(v);
  }
  __syncthreads();
#pragma unroll
  for (int i = 0; i < 4; ++i) {
    int dd = d0 + ty + i * 8;
    xT[(long)(b * DIN + dd) * NTOK + n0 + tx] = tile[tx][ty + i * 8];
  }
}

// ---------------------------------------------------------------------------
// Kernel 1: full projection GEMM via bf16 MFMA (4096 x 832 x 384), BK=64,
// double-buffered LDS, one barrier per k-iter, loads issued AFTER the barrier.
//   bn<12 : delta cols -> softplus+clamp, bf16, LDS-transpose, d-major planes
//   bn==12: B/C cols -> f32 TRANSPOSED planes BT/CT[s][4096] (float4 stores)
// ---------------------------------------------------------------------------
__global__ __launch_bounds__(256) void proj_mfma_kernel(
    const unsigned short* __restrict__ xb,   // bf16 x, row-major [4096][384]
    const unsigned short* __restrict__ Wb,   // bf16 W, row-major [832][384]
    const float* __restrict__ bdts, const float* __restrict__ bdtd,
    unsigned short* __restrict__ dsT, unsigned short* __restrict__ ddT,
    float* __restrict__ BT, float* __restrict__ CT)
{
  __shared__ short smem_s[2][2][64 * 72];   // [buf][A|W][64 rows x 72 pad] = 36864 B

  const int t    = threadIdx.x;
  const int bm   = blockIdx.x & 63;         // 64 row tiles
  const int bn   = blockIdx.x >> 6;         // 13 col tiles
  const int row0 = bm * 64;
  const int col0 = bn * 64;                 // 0..831
  const int bat  = row0 >> 10;
  const int n0   = row0 & 1023;

  const int l  = t & 63;
  const int w  = t >> 6;
  const int wr = (w >> 1) * 32;             // wave row base
  const int wc = (w & 1) * 32;              // wave col base
  const int lr = l & 15;
  const int lk = (l >> 4) * 8;              // k offset in frag (bf16)

  const int sr = t >> 2;                    // staging row 0..63
  const int sk = (t & 3) * 16;              // staging k (shorts), 2x uint4

  f32x4 acc[2][2];
  const f32x4 zero = {0.f, 0.f, 0.f, 0.f};
  acc[0][0] = zero; acc[0][1] = zero; acc[1][0] = zero; acc[1][1] = zero;

  uint4 la0, la1, lw0, lw1;
#define PLOAD(K0)                                                          \
  {                                                                        \
    const unsigned short* ap = &xb[(long)(row0 + sr) * KDIM + (K0) + sk];  \
    const unsigned short* wp = &Wb[(long)(col0 + sr) * KDIM + (K0) + sk];  \
    la0 = *(const uint4*)ap;  la1 = *(const uint4*)(ap + 8);               \
    lw0 = *(const uint4*)wp;  lw1 = *(const uint4*)(wp + 8);               \
  }
#define PSTORE(BUF)                                                        \
  {                                                                        \
    *(uint4*)&smem_s[BUF][0][sr * 72 + sk]     = la0;                      \
    *(uint4*)&smem_s[BUF][0][sr * 72 + sk + 8] = la1;                      \
    *(uint4*)&smem_s[BUF][1][sr * 72 + sk]     = lw0;                      \
    *(uint4*)&smem_s[BUF][1][sr * 72 + sk + 8] = lw1;                      \
  }

  PLOAD(0);
  PSTORE(0);

  for (int it = 0; it < 6; ++it) {
    const int cur = it & 1;
    __syncthreads();                        // lds[cur] visible; lds[cur^1] readers done
    if (it + 1 < 6) PLOAD((it + 1) * 64);   // in flight across MFMA + ds_write
    const short* Asm = smem_s[cur][0];
    const short* Wsm = smem_s[cur][1];
#pragma unroll
    for (int kh = 0; kh < 2; ++kh) {
      const int ko = kh * 32 + lk;
      bf16x8 a0 = *(const bf16x8*)&Asm[(wr + lr) * 72 + ko];
      bf16x8 a1 = *(const bf16x8*)&Asm[(wr + 16 + lr) * 72 + ko];
      bf16x8 b0 = *(const bf16x8*)&Wsm[(wc + lr) * 72 + ko];
      bf16x8 b1 = *(const bf16x8*)&Wsm[(wc + 16 + lr) * 72 + ko];
      acc[0][0] = __builtin_amdgcn_mfma_f32_16x16x32_bf16(a0, b0, acc[0][0], 0, 0, 0);
      acc[0][1] = __builtin_amdgcn_mfma_f32_16x16x32_bf16(a0, b1, acc[0][1], 0, 0, 0);
      acc[1][0] = __builtin_amdgcn_mfma_f32_16x16x32_bf16(a1, b0, acc[1][0], 0, 0, 0);
      acc[1][1] = __builtin_amdgcn_mfma_f32_16x16x32_bf16(a1, b1, acc[1][1], 0, 0, 0);
    }
    if (it + 1 < 6) PSTORE(cur ^ 1);        // vmcnt wait lands here, after MFMA
  }

  if (bn < 12) {
    const float* bias = (bn < 6) ? bdts : bdtd;
    unsigned short* plane = (bn < 6) ? dsT : ddT;
    const int dbase = (bn < 6) ? col0 : col0 - 384;
    const float bv0 = bias[dbase + wc + lr];
    const float bv1 = bias[dbase + wc + 16 + lr];
    __syncthreads();
    unsigned short* outl = (unsigned short*)smem_s;   // [64 d][72 n] u16
#pragma unroll
    for (int i = 0; i < 2; ++i)
#pragma unroll
      for (int j = 0; j < 2; ++j) {
        const float bb = j ? bv1 : bv0;
        const int cl = wc + j * 16 + lr;
#pragma unroll
        for (int q = 0; q < 4; ++q) {
          const int nl = wr + i * 16 + (l >> 4) * 4 + q;
          float dl = fminf(softplus_f(acc[i][j][q] + bb), 0.15f);
          outl[cl * 72 + nl] = f32_to_bf16(dl);
        }
      }
    __syncthreads();
    const int dl = t >> 2;
    const int seg = t & 3;
    uint4 w0 = *(const uint4*)&outl[dl * 72 + seg * 16];
    uint4 w1 = *(const uint4*)&outl[dl * 72 + seg * 16 + 8];
    long addr = (long)(bat * DIN + dbase + dl) * NTOK + n0 + seg * 16;
    *(uint4*)&plane[addr]     = w0;
    *(uint4*)&plane[addr + 8] = w1;
  } else {
    // B/C epilogue: transposed f32 planes, float4 per (i,j) fragment
#pragma unroll
    for (int i = 0; i < 2; ++i)
#pragma unroll
      for (int j = 0; j < 2; ++j) {
        const int cl = wc + j * 16 + lr;
        const int rowbase = row0 + wr + i * 16 + (l >> 4) * 4;
        if (cl < 16)       *(f32x4*)&BT[(long)cl * MROWS + rowbase] = acc[i][j];
        else if (cl < 32)  *(f32x4*)&CT[(long)(cl - 16) * MROWS + rowbase] = acc[i][j];
      }
  }
#undef PLOAD
#undef PSTORE
}

// ---------------------------------------------------------------------------
// Kernel 2: wave-parallel recurrence. Block = (b,d), 1024 thr = 16 waves,
// wave = one s-channel. Each lane owns a 4x4 patch of the 32x32 grid in f32
// REGISTERS; halo via __shfl; NO LDS/barriers in the k-loop (round 11-13:
// barrier+LDS designs pinned at 48us, VALUBusy 39%). Recurrence folded to
// h' = cA*h + g0 + a2*(u+d+l+r) with cA,g0,a2 precomputed per point.
// Single end barrier: partial y (per s) -> 64KB LDS -> cross-s reduce.
// NOTE: no 2nd launch_bounds arg (r9/r13: it force-caps VGPR -> spills).
// ---------------------------------------------------------------------------
__global__ __launch_bounds__(1024) void ssm_kernel(
    const float* __restrict__ xT,
    const unsigned short* __restrict__ dsT,
    const unsigned short* __restrict__ ddT,
    const float* __restrict__ BT, const float* __restrict__ CT,
    const float* __restrict__ Dparam, const float* __restrict__ Alog,
    const float* __restrict__ diffraw, const int* __restrict__ Kp,
    float* __restrict__ yT)
{
  __shared__ float P[16 * 1024];            // 65536 B partial plane
  const int t   = threadIdx.x;
  const int s   = t >> 6;                   // wave id = state channel
  const int l64 = t & 63;
  const int pr  = l64 >> 3, pc = l64 & 7;   // 8x8 lane grid, 4x4 patch each
  const int d = blockIdx.x % DIN;
  const int b = blockIdx.x / DIN;
  const int K = Kp[0];
  const float dt = 1.0f / (float)K;
  const float Dc = 0.5f / (1.0f + expf(-diffraw[d]));
  const float A  = -log1pf(expf(Alog[d * DST + s]));
  const float dtDc = dt * Dc;
  const long col = (long)(b * DIN + d) * NTOK;
  const long gr0 = (long)b * NTOK;
  const int  c0  = pc * 4;

  float h[16], cA[16], g0[16], a2v[16];
#pragma unroll
  for (int i = 0; i < 4; ++i) {
    const int n = (pr * 4 + i) * 32 + c0;
    float4 xv = *(const float4*)&xT[col + n];
    float4 bv = *(const float4*)&BT[(long)s * MROWS + gr0 + n];
    uint2 dsw = *(const uint2*)&dsT[col + n];
    uint2 ddw = *(const uint2*)&ddT[col + n];
    float dsf[4] = { bf16_lo(dsw.x), bf16_hi(dsw.x), bf16_lo(dsw.y), bf16_hi(dsw.y) };
    float ddf[4] = { bf16_lo(ddw.x), bf16_hi(ddw.x), bf16_lo(ddw.y), bf16_hi(ddw.y) };
    float xa[4] = { xv.x, xv.y, xv.z, xv.w };
    float ba[4] = { bv.x, bv.y, bv.z, bv.w };
#pragma unroll
    for (int j = 0; j < 4; ++j) {
      const int e = i * 4 + j;
      float a1 = dt * dsf[j];
      float a2 = dtDc * ddf[j];
      float h0 = xa[j] * ba[j];
      h[e]   = h0;
      g0[e]  = a1 * h0;
      a2v[e] = a2;
      cA[e]  = fmaf(a1, A, 1.0f) - 4.0f * a2;
    }
  }

  const int lu = (l64 - 8) & 63, ld = (l64 + 8) & 63;
  const int ll = (l64 - 1) & 63, lrr = (l64 + 1) & 63;

  for (int k = 0; k < K; ++k) {
    float up[4], dn[4], lf[4], rt[4];
#pragma unroll
    for (int j = 0; j < 4; ++j) {
      up[j] = __shfl(h[12 + j], lu);        // lane above's bottom row
      dn[j] = __shfl(h[j], ld);             // lane below's top row
      lf[j] = __shfl(h[4 * j + 3], ll);     // left lane's right col (j=i here)
      rt[j] = __shfl(h[4 * j], lrr);        // right lane's left col
    }
#pragma unroll
    for (int j = 0; j < 4; ++j) {           // replicate-pad at grid edges
      up[j] = (pr == 0) ? h[j]          : up[j];
      dn[j] = (pr == 7) ? h[12 + j]     : dn[j];
      lf[j] = (pc == 0) ? h[4 * j]      : lf[j];
      rt[j] = (pc == 7) ? h[4 * j + 3]  : rt[j];
    }
    float hn[16];
#pragma unroll
    for (int i = 0; i < 4; ++i)
#pragma unroll
      for (int j = 0; j < 4; ++j) {
        const int e = i * 4 + j;
        float uv = (i == 0) ? up[j] : h[e - 4];
        float dv = (i == 3) ? dn[j] : h[e + 4];
        float lv = (j == 0) ? lf[i] : h[e - 1];
        float rv = (j == 3) ? rt[i] : h[e + 1];
        float S  = (uv + dv) + (lv + rv);
        hn[e] = fmaf(cA[e], h[e], fmaf(a2v[e], S, g0[e]));
      }
#pragma unroll
    for (int e = 0; e < 16; ++e) h[e] = hn[e];
  }

  // per-s partial y into LDS
#pragma unroll
  for (int i = 0; i < 4; ++i) {
    const int n = (pr * 4 + i) * 32 + c0;
    float4 cv = *(const float4*)&CT[(long)s * MROWS + gr0 + n];
    float4 pv;
    pv.x = h[i * 4 + 0] * cv.x;
    pv.y = h[i * 4 + 1] * cv.y;
    pv.z = h[i * 4 + 2] * cv.z;
    pv.w = h[i * 4 + 3] * cv.w;
    *(float4*)&P[s * 1024 + n] = pv;
  }
  __syncthreads();

  // cross-s reduce + residual; thread t owns point n = t
  {
    float sum = 0.f;
#pragma unroll
    for (int ss = 0; ss < 16; ++ss) sum += P[ss * 1024 + t];
    yT[col + t] = fmaf(xT[col + t], Dparam[d], sum);
  }
}

// ---------------------------------------------------------------------------
// Kernel 3: yT (b,d,n) -> out (b,n,d), both sides coalesced via LDS tile.
// ---------------------------------------------------------------------------
__global__ __launch_bounds__(256) void untranspose_kernel(
    const float* __restrict__ yT, float* __restrict__ out)
{
  __shared__ float tile[32][33];
  const int n0 = blockIdx.x * 32;
  const int d0 = blockIdx.y * 32;
  const int b  = blockIdx.z;
  const int tx = threadIdx.x & 31, ty = threadIdx.x >> 5;
#pragma unroll
  for (int i = 0; i < 4; ++i) {
    int dd = d0 + ty + i * 8;
    tile[ty + i * 8][tx] = yT[(long)(b * DIN + dd) * NTOK + n0 + tx];
  }
  __syncthreads();
#pragma unroll
  for (int i = 0; i < 4; ++i) {
    int nn = n0 + ty + i * 8;
    out[(long)(b * NTOK + nn) * DIN + d0 + tx] = tile[tx][ty + i * 8];
  }
}

extern "C" void kernel_launch(void* const* d_in, const int* in_sizes, int n_in,
                              void* d_out, int out_size, void* d_ws, size_t ws_size,
                              hipStream_t stream) {
  const float* x     = (const float*)d_in[0];
  const float* Wdts  = (const float*)d_in[1];
  const float* bdts  = (const float*)d_in[2];
  const float* Wdtd  = (const float*)d_in[3];
  const float* bdtd  = (const float*)d_in[4];
  const float* WB    = (const float*)d_in[5];
  const float* WC    = (const float*)d_in[6];
  const float* Dpar  = (const float*)d_in[7];
  const float* Alog  = (const float*)d_in[8];
  const float* diffr = (const float*)d_in[9];
  const int*   Kst   = (const int*)d_in[10];

  // ws layout (13.1 MB): BT | CT | xT | yT.  xb+Wb alias the yT region
  // (dead until ssm writes yT — stream-ordered).
  float* BT = (float*)d_ws;                        // [16][4096]
  float* CT = BT + (long)DST * MROWS;              // [16][4096]
  float* xT = CT + (long)DST * MROWS;
  float* yT = xT + NM;
  unsigned short* xb = (unsigned short*)yT;        // NM bf16 (3.1 MB)
  unsigned short* Wb = xb + NM;                    // 832*384 bf16 (0.64 MB)

  // d_out scratch: bf16 delta planes between proj and ssm
  unsigned short* dsT = (unsigned short*)d_out;
  unsigned short* ddT = dsT + NM;

  wconv_kernel<<<dim3(156), dim3(256), 0, stream>>>(Wdts, Wdtd, WB, WC, Wb);

  xpose_kernel<<<dim3(NTOK / 32, DIN / 32, BSZ), dim3(256), 0, stream>>>(x, xT, xb);

  proj_mfma_kernel<<<dim3(64 * 13), dim3(256), 0, stream>>>(
      xb, Wb, bdts, bdtd, dsT, ddT, BT, CT);

  ssm_kernel<<<dim3(BSZ * DIN), dim3(1024), 0, stream>>>(
      xT, dsT, ddT, BT, CT, Dpar, Alog, diffr, Kst, yT);

  untranspose_kernel<<<dim3(NTOK / 32, DIN / 32, BSZ), dim3(256), 0, stream>>>(
      yT, (float*)d_out);
}

// Round 16
// 68.039 us; speedup vs baseline: 2.3415x; 1.0977x over previous
//
#include <hip/hip_runtime.h>
#include <hip/hip_bf16.h>

#define BSZ   4
#define NTOK  1024
#define DIN   384
#define DST   16
#define MROWS (BSZ * NTOK)     // 4096
#define KDIM  384
#define NM    (MROWS * DIN)    // 1572864 elements per plane

typedef __attribute__((ext_vector_type(8))) short bf16x8;
typedef __attribute__((ext_vector_type(4))) float f32x4;

__device__ __forceinline__ float softplus_f(float z) {
  return (z > 20.0f) ? z : log1pf(expf(z));
}

__device__ __forceinline__ unsigned short f32_to_bf16(float f) {
  unsigned int u = __float_as_uint(f);
  unsigned int rnd = 0x7fffu + ((u >> 16) & 1u);   // round-to-nearest-even
  return (unsigned short)((u + rnd) >> 16);
}

__device__ __forceinline__ float bf16_lo(unsigned int w) { return __uint_as_float(w << 16); }
__device__ __forceinline__ float bf16_hi(unsigned int w) { return __uint_as_float(w & 0xffff0000u); }

// ---------------------------------------------------------------------------
// Kernel W: concat(Wdts|Wdtd|WB|WC|0) f32 -> bf16 rows Wb[832][384]
// ---------------------------------------------------------------------------
__global__ __launch_bounds__(256) void wconv_kernel(
    const float* __restrict__ Wdts, const float* __restrict__ Wdtd,
    const float* __restrict__ WB,   const float* __restrict__ WC,
    unsigned short* __restrict__ Wb)
{
  const int idx8 = (blockIdx.x * 256 + threadIdx.x) * 8;   // 156 blocks
  const int row = idx8 / KDIM;
  const int k   = idx8 % KDIM;
  uint4 o = make_uint4(0u, 0u, 0u, 0u);
  if (row < 800) {
    const float* src;
    if (row < 384)      src = Wdts + (long)row * KDIM + k;
    else if (row < 768) src = Wdtd + (long)(row - 384) * KDIM + k;
    else if (row < 784) src = WB   + (long)(row - 768) * KDIM + k;
    else                src = WC   + (long)(row - 784) * KDIM + k;
    float4 v0 = *(const float4*)src;
    float4 v1 = *(const float4*)(src + 4);
    o.x = (unsigned int)f32_to_bf16(v0.x) | ((unsigned int)f32_to_bf16(v0.y) << 16);
    o.y = (unsigned int)f32_to_bf16(v0.z) | ((unsigned int)f32_to_bf16(v0.w) << 16);
    o.z = (unsigned int)f32_to_bf16(v1.x) | ((unsigned int)f32_to_bf16(v1.y) << 16);
    o.w = (unsigned int)f32_to_bf16(v1.z) | ((unsigned int)f32_to_bf16(v1.w) << 16);
  }
  *(uint4*)&Wb[idx8] = o;
}

// ---------------------------------------------------------------------------
// Kernel 0: x (b,n,d) -> xT (b,d,n) f32  AND  xb (b,n,d) bf16 (for MFMA).
// ---------------------------------------------------------------------------
__global__ __launch_bounds__(256) void xpose_kernel(
    const float* __restrict__ x, float* __restrict__ xT,
    unsigned short* __restrict__ xb)
{
  __shared__ float tile[32][33];
  const int n0 = blockIdx.x * 32;
  const int d0 = blockIdx.y * 32;
  const int b  = blockIdx.z;
  const int tx = threadIdx.x & 31, ty = threadIdx.x >> 5;   // ty 0..7
#pragma unroll
  for (int i = 0; i < 4; ++i) {
    int nn = n0 + ty + i * 8;
    float v = x[(long)(b * NTOK + nn) * DIN + d0 + tx];
    tile[ty + i * 8][tx] = v;
    xb[(long)(b * NTOK + nn) * DIN + d0 + tx] = f32_to_bf16(v);
  }
  __syncthreads();
#pragma unroll
  for (int i = 0; i < 4; ++i) {
    int dd = d0 + ty + i * 8;
    xT[(long)(b * DIN + dd) * NTOK + n0 + tx] = tile[tx][ty + i * 8];
  }
}

// ---------------------------------------------------------------------------
// Kernel 1: full projection GEMM via bf16 MFMA (4096 x 832 x 384), BK=64,
// double-buffered LDS, one barrier per k-iter, loads issued AFTER the barrier.
//   bn<12 : delta cols -> softplus+clamp, bf16, LDS-transpose, d-major planes
//   bn==12: B/C cols -> f32 TRANSPOSED planes BT/CT[s][4096] (float4 stores)
// ---------------------------------------------------------------------------
__global__ __launch_bounds__(256) void proj_mfma_kernel(
    const unsigned short* __restrict__ xb,   // bf16 x, row-major [4096][384]
    const unsigned short* __restrict__ Wb,   // bf16 W, row-major [832][384]
    const float* __restrict__ bdts, const float* __restrict__ bdtd,
    unsigned short* __restrict__ dsT, unsigned short* __restrict__ ddT,
    float* __restrict__ BT, float* __restrict__ CT)
{
  __shared__ short smem_s[2][2][64 * 72];   // [buf][A|W][64 rows x 72 pad] = 36864 B

  const int t    = threadIdx.x;
  const int bm   = blockIdx.x & 63;         // 64 row tiles
  const int bn   = blockIdx.x >> 6;         // 13 col tiles
  const int row0 = bm * 64;
  const int col0 = bn * 64;                 // 0..831
  const int bat  = row0 >> 10;
  const int n0   = row0 & 1023;

  const int l  = t & 63;
  const int w  = t >> 6;
  const int wr = (w >> 1) * 32;             // wave row base
  const int wc = (w & 1) * 32;              // wave col base
  const int lr = l & 15;
  const int lk = (l >> 4) * 8;              // k offset in frag (bf16)

  const int sr = t >> 2;                    // staging row 0..63
  const int sk = (t & 3) * 16;              // staging k (shorts), 2x uint4

  f32x4 acc[2][2];
  const f32x4 zero = {0.f, 0.f, 0.f, 0.f};
  acc[0][0] = zero; acc[0][1] = zero; acc[1][0] = zero; acc[1][1] = zero;

  uint4 la0, la1, lw0, lw1;
#define PLOAD(K0)                                                          \
  {                                                                        \
    const unsigned short* ap = &xb[(long)(row0 + sr) * KDIM + (K0) + sk];  \
    const unsigned short* wp = &Wb[(long)(col0 + sr) * KDIM + (K0) + sk];  \
    la0 = *(const uint4*)ap;  la1 = *(const uint4*)(ap + 8);               \
    lw0 = *(const uint4*)wp;  lw1 = *(const uint4*)(wp + 8);               \
  }
#define PSTORE(BUF)                                                        \
  {                                                                        \
    *(uint4*)&smem_s[BUF][0][sr * 72 + sk]     = la0;                      \
    *(uint4*)&smem_s[BUF][0][sr * 72 + sk + 8] = la1;                      \
    *(uint4*)&smem_s[BUF][1][sr * 72 + sk]     = lw0;                      \
    *(uint4*)&smem_s[BUF][1][sr * 72 + sk + 8] = lw1;                      \
  }

  PLOAD(0);
  PSTORE(0);

  for (int it = 0; it < 6; ++it) {
    const int cur = it & 1;
    __syncthreads();                        // lds[cur] visible; lds[cur^1] readers done
    if (it + 1 < 6) PLOAD((it + 1) * 64);   // in flight across MFMA + ds_write
    const short* Asm = smem_s[cur][0];
    const short* Wsm = smem_s[cur][1];
#pragma unroll
    for (int kh = 0; kh < 2; ++kh) {
      const int ko = kh * 32 + lk;
      bf16x8 a0 = *(const bf16x8*)&Asm[(wr + lr) * 72 + ko];
      bf16x8 a1 = *(const bf16x8*)&Asm[(wr + 16 + lr) * 72 + ko];
      bf16x8 b0 = *(const bf16x8*)&Wsm[(wc + lr) * 72 + ko];
      bf16x8 b1 = *(const bf16x8*)&Wsm[(wc + 16 + lr) * 72 + ko];
      acc[0][0] = __builtin_amdgcn_mfma_f32_16x16x32_bf16(a0, b0, acc[0][0], 0, 0, 0);
      acc[0][1] = __builtin_amdgcn_mfma_f32_16x16x32_bf16(a0, b1, acc[0][1], 0, 0, 0);
      acc[1][0] = __builtin_amdgcn_mfma_f32_16x16x32_bf16(a1, b0, acc[1][0], 0, 0, 0);
      acc[1][1] = __builtin_amdgcn_mfma_f32_16x16x32_bf16(a1, b1, acc[1][1], 0, 0, 0);
    }
    if (it + 1 < 6) PSTORE(cur ^ 1);        // vmcnt wait lands here, after MFMA
  }

  if (bn < 12) {
    const float* bias = (bn < 6) ? bdts : bdtd;
    unsigned short* plane = (bn < 6) ? dsT : ddT;
    const int dbase = (bn < 6) ? col0 : col0 - 384;
    const float bv0 = bias[dbase + wc + lr];
    const float bv1 = bias[dbase + wc + 16 + lr];
    __syncthreads();
    unsigned short* outl = (unsigned short*)smem_s;   // [64 d][72 n] u16
#pragma unroll
    for (int i = 0; i < 2; ++i)
#pragma unroll
      for (int j = 0; j < 2; ++j) {
        const float bb = j ? bv1 : bv0;
        const int cl = wc + j * 16 + lr;
#pragma unroll
        for (int q = 0; q < 4; ++q) {
          const int nl = wr + i * 16 + (l >> 4) * 4 + q;
          float dl = fminf(softplus_f(acc[i][j][q] + bb), 0.15f);
          outl[cl * 72 + nl] = f32_to_bf16(dl);
        }
      }
    __syncthreads();
    const int dl = t >> 2;
    const int seg = t & 3;
    uint4 w0 = *(const uint4*)&outl[dl * 72 + seg * 16];
    uint4 w1 = *(const uint4*)&outl[dl * 72 + seg * 16 + 8];
    long addr = (long)(bat * DIN + dbase + dl) * NTOK + n0 + seg * 16;
    *(uint4*)&plane[addr]     = w0;
    *(uint4*)&plane[addr + 8] = w1;
  } else {
    // B/C epilogue: transposed f32 planes, float4 per (i,j) fragment
#pragma unroll
    for (int i = 0; i < 2; ++i)
#pragma unroll
      for (int j = 0; j < 2; ++j) {
        const int cl = wc + j * 16 + lr;
        const int rowbase = row0 + wr + i * 16 + (l >> 4) * 4;
        if (cl < 16)       *(f32x4*)&BT[(long)cl * MROWS + rowbase] = acc[i][j];
        else if (cl < 32)  *(f32x4*)&CT[(long)(cl - 16) * MROWS + rowbase] = acc[i][j];
      }
  }
#undef PLOAD
#undef PSTORE
}

// ---------------------------------------------------------------------------
// Kernel 2: wave-parallel recurrence, HALF-SPLIT. Block = (b,d,shalf):
// 512 thr = 8 waves = 8 s-channels. Lane owns a 4x4 f32 register patch of the
// 32x32 grid; halo via __shfl; no LDS/barriers in k-loop. End: LDS-reduce the
// 8 partials (P[8][1024] = 32 KB) and write a bf16 partial-y plane yH[shalf].
// 4 blocks/CU resident (2048 thr, 128 KB LDS) vs round-14's 2 (occ 38%).
// untranspose sums yH0+yH1 and adds the x*D residual.
// NOTE: no 2nd launch_bounds arg (r9/r13: it force-caps VGPR -> spills).
// ---------------------------------------------------------------------------
__global__ __launch_bounds__(512) void ssm_kernel(
    const float* __restrict__ xT,
    const unsigned short* __restrict__ dsT,
    const unsigned short* __restrict__ ddT,
    const float* __restrict__ BT, const float* __restrict__ CT,
    const float* __restrict__ Alog,
    const float* __restrict__ diffraw, const int* __restrict__ Kp,
    unsigned short* __restrict__ yH0, unsigned short* __restrict__ yH1)
{
  __shared__ float P[8 * 1024];             // 32768 B partial plane
  const int bid   = blockIdx.x;
  const int shalf = bid & 1;
  const int bd    = bid >> 1;
  const int d = bd % DIN;
  const int b = bd / DIN;
  const int t   = threadIdx.x;              // 0..511
  const int s   = shalf * 8 + (t >> 6);     // global state channel
  const int l64 = t & 63;
  const int pr  = l64 >> 3, pc = l64 & 7;   // 8x8 lane grid, 4x4 patch each
  const int K = Kp[0];
  const float dt = 1.0f / (float)K;
  const float Dc = 0.5f / (1.0f + expf(-diffraw[d]));
  const float A  = -log1pf(expf(Alog[d * DST + s]));
  const float dtDc = dt * Dc;
  const long col = (long)(b * DIN + d) * NTOK;
  const long gr0 = (long)b * NTOK;
  const int  c0  = pc * 4;

  float h[16], cA[16], g0[16], a2v[16];
#pragma unroll
  for (int i = 0; i < 4; ++i) {
    const int n = (pr * 4 + i) * 32 + c0;
    float4 xv = *(const float4*)&xT[col + n];
    float4 bv = *(const float4*)&BT[(long)s * MROWS + gr0 + n];
    uint2 dsw = *(const uint2*)&dsT[col + n];
    uint2 ddw = *(const uint2*)&ddT[col + n];
    float dsf[4] = { bf16_lo(dsw.x), bf16_hi(dsw.x), bf16_lo(dsw.y), bf16_hi(dsw.y) };
    float ddf[4] = { bf16_lo(ddw.x), bf16_hi(ddw.x), bf16_lo(ddw.y), bf16_hi(ddw.y) };
    float xa[4] = { xv.x, xv.y, xv.z, xv.w };
    float ba[4] = { bv.x, bv.y, bv.z, bv.w };
#pragma unroll
    for (int j = 0; j < 4; ++j) {
      const int e = i * 4 + j;
      float a1 = dt * dsf[j];
      float a2 = dtDc * ddf[j];
      float h0 = xa[j] * ba[j];
      h[e]   = h0;
      g0[e]  = a1 * h0;
      a2v[e] = a2;
      cA[e]  = fmaf(a1, A, 1.0f) - 4.0f * a2;
    }
  }

  const int lu = (l64 - 8) & 63, ld = (l64 + 8) & 63;
  const int ll = (l64 - 1) & 63, lrr = (l64 + 1) & 63;

  for (int k = 0; k < K; ++k) {
    float up[4], dn[4], lf[4], rt[4];
#pragma unroll
    for (int j = 0; j < 4; ++j) {
      up[j] = __shfl(h[12 + j], lu);        // lane above's bottom row
      dn[j] = __shfl(h[j], ld);             // lane below's top row
      lf[j] = __shfl(h[4 * j + 3], ll);     // left lane's right col
      rt[j] = __shfl(h[4 * j], lrr);        // right lane's left col
    }
#pragma unroll
    for (int j = 0; j < 4; ++j) {           // replicate-pad at grid edges
      up[j] = (pr == 0) ? h[j]          : up[j];
      dn[j] = (pr == 7) ? h[12 + j]     : dn[j];
      lf[j] = (pc == 0) ? h[4 * j]      : lf[j];
      rt[j] = (pc == 7) ? h[4 * j + 3]  : rt[j];
    }
    float hn[16];
#pragma unroll
    for (int i = 0; i < 4; ++i)
#pragma unroll
      for (int j = 0; j < 4; ++j) {
        const int e = i * 4 + j;
        float uv = (i == 0) ? up[j] : h[e - 4];
        float dv = (i == 3) ? dn[j] : h[e + 4];
        float lv = (j == 0) ? lf[i] : h[e - 1];
        float rv = (j == 3) ? rt[i] : h[e + 1];
        float S  = (uv + dv) + (lv + rv);
        hn[e] = fmaf(cA[e], h[e], fmaf(a2v[e], S, g0[e]));
      }
#pragma unroll
    for (int e = 0; e < 16; ++e) h[e] = hn[e];
  }

  // per-s partial y into LDS (wave index = s & 7)
  const int sw = t >> 6;
#pragma unroll
  for (int i = 0; i < 4; ++i) {
    const int n = (pr * 4 + i) * 32 + c0;
    float4 cv = *(const float4*)&CT[(long)s * MROWS + gr0 + n];
    float4 pv;
    pv.x = h[i * 4 + 0] * cv.x;
    pv.y = h[i * 4 + 1] * cv.y;
    pv.z = h[i * 4 + 2] * cv.z;
    pv.w = h[i * 4 + 3] * cv.w;
    *(float4*)&P[sw * 1024 + n] = pv;
  }
  __syncthreads();

  // reduce 8 partials; thread t owns points t and t+512
  unsigned short* yH = shalf ? yH1 : yH0;
  float s0 = 0.f, s1 = 0.f;
#pragma unroll
  for (int ss = 0; ss < 8; ++ss) {
    s0 += P[ss * 1024 + t];
    s1 += P[ss * 1024 + t + 512];
  }
  yH[col + t]       = f32_to_bf16(s0);
  yH[col + t + 512] = f32_to_bf16(s1);
}

// ---------------------------------------------------------------------------
// Kernel 3: out(b,n,d) = yH0 + yH1 + x*D, transposed via LDS tile.
// ---------------------------------------------------------------------------
__global__ __launch_bounds__(256) void untranspose_kernel(
    const unsigned short* __restrict__ yH0,
    const unsigned short* __restrict__ yH1,
    const float* __restrict__ xT, const float* __restrict__ Dparam,
    float* __restrict__ out)
{
  __shared__ float tile[32][33];
  const int n0 = blockIdx.x * 32;
  const int d0 = blockIdx.y * 32;
  const int b  = blockIdx.z;
  const int tx = threadIdx.x & 31, ty = threadIdx.x >> 5;
#pragma unroll
  for (int i = 0; i < 4; ++i) {
    int dd = d0 + ty + i * 8;
    long idx = (long)(b * DIN + dd) * NTOK + n0 + tx;
    float v0 = __uint_as_float((unsigned int)yH0[idx] << 16);
    float v1 = __uint_as_float((unsigned int)yH1[idx] << 16);
    tile[ty + i * 8][tx] = v0 + v1 + xT[idx] * Dparam[dd];
  }
  __syncthreads();
#pragma unroll
  for (int i = 0; i < 4; ++i) {
    int nn = n0 + ty + i * 8;
    out[(long)(b * NTOK + nn) * DIN + d0 + tx] = tile[tx][ty + i * 8];
  }
}

extern "C" void kernel_launch(void* const* d_in, const int* in_sizes, int n_in,
                              void* d_out, int out_size, void* d_ws, size_t ws_size,
                              hipStream_t stream) {
  const float* x     = (const float*)d_in[0];
  const float* Wdts  = (const float*)d_in[1];
  const float* bdts  = (const float*)d_in[2];
  const float* Wdtd  = (const float*)d_in[3];
  const float* bdtd  = (const float*)d_in[4];
  const float* WB    = (const float*)d_in[5];
  const float* WC    = (const float*)d_in[6];
  const float* Dpar  = (const float*)d_in[7];
  const float* Alog  = (const float*)d_in[8];
  const float* diffr = (const float*)d_in[9];
  const int*   Kst   = (const int*)d_in[10];

  // ws layout (13.1 MB): BT | CT | xT | yH0,yH1 (bf16).  xb+Wb alias the yH
  // region (dead until ssm writes yH — stream-ordered).
  float* BT = (float*)d_ws;                        // [16][4096]
  float* CT = BT + (long)DST * MROWS;              // [16][4096]
  float* xT = CT + (long)DST * MROWS;
  unsigned short* yH0 = (unsigned short*)(xT + NM);   // NM u16
  unsigned short* yH1 = yH0 + NM;                     // NM u16
  unsigned short* xb  = yH0;                          // alias (pre-ssm)
  unsigned short* Wb  = xb + NM;                      // 832*384 bf16

  // d_out scratch: bf16 delta planes between proj and ssm
  unsigned short* dsT = (unsigned short*)d_out;
  unsigned short* ddT = dsT + NM;

  wconv_kernel<<<dim3(156), dim3(256), 0, stream>>>(Wdts, Wdtd, WB, WC, Wb);

  xpose_kernel<<<dim3(NTOK / 32, DIN / 32, BSZ), dim3(256), 0, stream>>>(x, xT, xb);

  proj_mfma_kernel<<<dim3(64 * 13), dim3(256), 0, stream>>>(
      xb, Wb, bdts, bdtd, dsT, ddT, BT, CT);

  ssm_kernel<<<dim3(BSZ * DIN * 2), dim3(512), 0, stream>>>(
      xT, dsT, ddT, BT, CT, Alog, diffr, Kst, yH0, yH1);

  untranspose_kernel<<<dim3(NTOK / 32, DIN / 32, BSZ), dim3(256), 0, stream>>>(
      yH0, yH1, xT, Dpar, (float*)d_out);
}